// Round 5
// baseline (828.590 us; speedup 1.0000x reference)
//
#include <hip/hip_runtime.h>

typedef __bf16 bf16x8 __attribute__((ext_vector_type(8)));
typedef float f32x4 __attribute__((ext_vector_type(4)));

constexpr int NN = 50000;   // nodes
constexpr int NE = 800000;  // edges
constexpr int DIN = 256, DHID = 256, DOUT = 128;
constexpr int NCH = (NN + 255) / 256;  // 196 chunks of 256

__device__ __forceinline__ unsigned short f2bf(float f) {
  unsigned u = __float_as_uint(f);
  u += 0x7fffu + ((u >> 16) & 1u);  // RNE
  return (unsigned short)(u >> 16);
}
__device__ __forceinline__ float bf2f(unsigned short h) {
  return __uint_as_float(((unsigned)h) << 16);
}

// ---------------- CSR build ----------------

__global__ void hist_kernel(const int* __restrict__ e0, const int* __restrict__ e1,
                            int* __restrict__ counts) {
  int g = blockIdx.y;
  const int* dst = (g ? e1 : e0) + NE;  // edge_index row 1
  int* c = counts + g * NN;
  int i = blockIdx.x * blockDim.x + threadIdx.x;
  if (i < NE) atomicAdd(&c[dst[i]], 1);
}

// 3-phase hierarchical exclusive scan of counts -> rowptr/cursor (+dinv)

__global__ __launch_bounds__(256) void scanA_kernel(const int* __restrict__ counts,
                                                    int* __restrict__ bsum) {
  int g = blockIdx.y, chunk = blockIdx.x, t = threadIdx.x;
  int i = chunk * 256 + t;
  int v = (i < NN) ? counts[g * NN + i] : 0;
  __shared__ int sh[256];
  sh[t] = v;
  __syncthreads();
  for (int off = 128; off > 0; off >>= 1) {
    if (t < off) sh[t] += sh[t + off];
    __syncthreads();
  }
  if (t == 0) bsum[g * NCH + chunk] = sh[0];
}

__global__ __launch_bounds__(256) void scanB_kernel(int* __restrict__ bsum,
                                                    int* __restrict__ rowptr) {
  int g = blockIdx.x, t = threadIdx.x;
  int v = (t < NCH) ? bsum[g * NCH + t] : 0;
  __shared__ int sh[256];
  sh[t] = v;
  __syncthreads();
  for (int off = 1; off < 256; off <<= 1) {
    int x = (t >= off) ? sh[t - off] : 0;
    __syncthreads();
    if (t >= off) sh[t] += x;
    __syncthreads();
  }
  if (t < NCH) bsum[g * NCH + t] = sh[t] - v;  // exclusive base
  if (t == 255) rowptr[g * (NN + 1) + NN] = sh[255];
}

__global__ __launch_bounds__(256) void scanC_kernel(const int* __restrict__ counts,
                                                    const int* __restrict__ bsum,
                                                    int* __restrict__ rowptr,
                                                    int* __restrict__ cursor,
                                                    float* __restrict__ dinv) {
  int g = blockIdx.y, chunk = blockIdx.x, t = threadIdx.x;
  int i = chunk * 256 + t;
  int v = (i < NN) ? counts[g * NN + i] : 0;
  __shared__ int sh[256];
  sh[t] = v;
  __syncthreads();
  for (int off = 1; off < 256; off <<= 1) {
    int x = (t >= off) ? sh[t - off] : 0;
    __syncthreads();
    if (t >= off) sh[t] += x;
    __syncthreads();
  }
  if (i < NN) {
    int run = bsum[g * NCH + chunk] + sh[t] - v;
    rowptr[g * (NN + 1) + i] = run;
    cursor[g * NN + i] = run;
    dinv[g * NN + i] = rsqrtf((float)(v + 1));  // +1 self-loop
  }
}

__global__ void scatter_kernel(const int* __restrict__ e0, const int* __restrict__ e1,
                               int* __restrict__ cursor, unsigned short* __restrict__ col) {
  int g = blockIdx.y;
  const int* e = g ? e1 : e0;
  int* cur = cursor + g * NN;
  unsigned short* cl = col + g * NE;
  int i = blockIdx.x * blockDim.x + threadIdx.x;
  if (i < NE) {
    int s = e[i], d = e[NE + i];
    int slot = atomicAdd(&cur[d], 1);
    cl[slot] = (unsigned short)s;
  }
}

// ---------------- Pack W into B-fragment order ----------------

__global__ void pack_kernel(const float* __restrict__ W1, const float* __restrict__ W2,
                            unsigned short* __restrict__ P1, unsigned short* __restrict__ P2) {
  int i = blockIdx.x * blockDim.x + threadIdx.x;
  constexpr int N1 = 8 * 16 * 64 * 8;  // 65536 (K=256, N=256)
  constexpr int N2 = 8 * 8 * 64 * 8;   // 32768 (K=256, N=128)
  if (i < N1) {
    int j = i & 7, lane = (i >> 3) & 63, grp = i >> 9;
    int nt = grp & 15, kb = grp >> 4;
    int k = kb * 32 + (lane >> 4) * 8 + j;
    int n = nt * 16 + (lane & 15);
    P1[i] = f2bf(W1[k * DHID + n]);
  } else if (i < N1 + N2) {
    int ii = i - N1;
    int j = ii & 7, lane = (ii >> 3) & 63, grp = ii >> 9;
    int nt = grp & 7, kb = grp >> 3;
    int k = kb * 32 + (lane >> 4) * 8 + j;
    int n = nt * 16 + (lane & 15);
    P2[ii] = f2bf(W2[k * DOUT + n]);
  }
}

// ---------------- MFMA matmul: C[M,N] = (A[M,256] @ W) * dinv[row] ----------------

template <int N, bool AF32>
__global__ __launch_bounds__(256) void mm_kernel(
    const void* __restrict__ A0, const void* __restrict__ A1,
    const unsigned short* __restrict__ Wp, unsigned short* __restrict__ Cb,
    const float* __restrict__ dinv, long long gstride) {
  constexpr int NT = N / 16;
  constexpr int K = 256;
  int g = blockIdx.y;
  const void* A = g ? A1 : A0;
  unsigned short* C = Cb + (size_t)g * gstride;
  const float* dv = dinv + g * NN;
  int wave = threadIdx.x >> 6, lane = threadIdx.x & 63;
  int q = lane >> 4, lm = lane & 15;
  int m0 = blockIdx.x * 64 + wave * 16;
  int row = m0 + lm;
  int rowc = min(row, NN - 1);
  f32x4 acc[NT];
#pragma unroll
  for (int nt = 0; nt < NT; nt++) acc[nt] = (f32x4){0.f, 0.f, 0.f, 0.f};
#pragma unroll
  for (int kb = 0; kb < K / 32; kb++) {
    int kc = kb * 32 + q * 8;  // lane's contiguous k-chunk (A frag: k = quad*8+j)
    bf16x8 a;
    if constexpr (AF32) {
      const float* Af = (const float*)A + (size_t)rowc * K + kc;
      const float4 v0 = *(const float4*)Af;
      const float4 v1 = *(const float4*)(Af + 4);
      a[0] = (__bf16)v0.x; a[1] = (__bf16)v0.y; a[2] = (__bf16)v0.z; a[3] = (__bf16)v0.w;
      a[4] = (__bf16)v1.x; a[5] = (__bf16)v1.y; a[6] = (__bf16)v1.z; a[7] = (__bf16)v1.w;
    } else {
      const unsigned short* Ab = (const unsigned short*)A + (size_t)rowc * K + kc;
      a = *(const bf16x8*)Ab;
    }
#pragma unroll
    for (int nt = 0; nt < NT; nt++) {
      bf16x8 b = *(const bf16x8*)(Wp + (((size_t)kb * NT + nt) * 64 + lane) * 8);
      acc[nt] = __builtin_amdgcn_mfma_f32_16x16x32_bf16(a, b, acc[nt], 0, 0, 0);
    }
  }
  // C/D layout: col = lane&15, row = quad*4 + reg
  float dvr[4];
#pragma unroll
  for (int r = 0; r < 4; r++) dvr[r] = dv[min(m0 + q * 4 + r, NN - 1)];
#pragma unroll
  for (int nt = 0; nt < NT; nt++) {
#pragma unroll
    for (int r = 0; r < 4; r++) {
      int grow = m0 + q * 4 + r;
      if (grow < NN) C[(size_t)grow * N + nt * 16 + lm] = f2bf(acc[nt][r] * dvr[r]);
    }
  }
}

// ---------------- Sliced aggregation (gather over CSR) ----------------
// Column-sliced for XCD-L2 residency: slice = blockIdx.x % NSL -> round-robin
// lands all blocks of slice s on XCD (s % 8); slice working set = 50000 rows
// x 64 B = 3.2 MB < 4 MB per-XCD L2. Wave = 4 edge-groups x 16 lanes; each
// group gathers one source row slice (16 lanes x dword = 64 B); 16-edge
// unrolled loop keeps 4 gathers in flight; shfl_xor reduces over groups.
// Rows pre-scaled by dinv[src] (mm epilogue); epilogue scales by dinv[node].

template <int D, int NSL, bool RELU, typename OutT>
__global__ __launch_bounds__(256) void agg_kernel(
    const unsigned short* __restrict__ Hb, OutT* __restrict__ Ob,
    const int* __restrict__ rowptr, const unsigned short* __restrict__ col,
    const float* __restrict__ dinv, const float* __restrict__ bias,
    long long hgstride, long long ogstride) {
  constexpr int CHUNKS = NN / 4;  // 12500, block covers 4 nodes (1/wave)
  int x = blockIdx.x;
  int slice = x % NSL;
  int rest = x / NSL;
  int g = rest / CHUNKS;
  int chunk = rest - g * CHUNKS;
  int wave = threadIdx.x >> 6, lane = threadIdx.x & 63;
  int eg = lane >> 4, l16 = lane & 15;
  int node = chunk * 4 + wave;
  const unsigned short* H = Hb + (size_t)g * hgstride;
  const int* rp = rowptr + g * (NN + 1);
  const unsigned short* cl = col + (size_t)g * NE;
  int co = slice * 32 + l16 * 2;  // column offset in elements (dword per lane)
  int jb = rp[node], je = rp[node + 1];
  float acc0 = 0.f, acc1 = 0.f;
  int j = jb;
  for (; j + 16 <= je; j += 16) {
    int s[4];
    unsigned d[4];
#pragma unroll
    for (int u = 0; u < 4; u++) s[u] = cl[j + u * 4 + eg];
#pragma unroll
    for (int u = 0; u < 4; u++) d[u] = *(const unsigned*)(H + (size_t)s[u] * D + co);
#pragma unroll
    for (int u = 0; u < 4; u++) {
      acc0 += __uint_as_float(d[u] << 16);
      acc1 += __uint_as_float(d[u] & 0xffff0000u);
    }
  }
  if (j + 8 <= je) {
    int s0 = cl[j + eg], s1 = cl[j + 4 + eg];
    unsigned d0 = *(const unsigned*)(H + (size_t)s0 * D + co);
    unsigned d1 = *(const unsigned*)(H + (size_t)s1 * D + co);
    acc0 += __uint_as_float(d0 << 16) + __uint_as_float(d1 << 16);
    acc1 += __uint_as_float(d0 & 0xffff0000u) + __uint_as_float(d1 & 0xffff0000u);
    j += 8;
  }
  if (j + 4 <= je) {
    int s0 = cl[j + eg];
    unsigned d0 = *(const unsigned*)(H + (size_t)s0 * D + co);
    acc0 += __uint_as_float(d0 << 16);
    acc1 += __uint_as_float(d0 & 0xffff0000u);
    j += 4;
  }
  if (j + eg < je) {
    int s0 = cl[j + eg];
    unsigned d0 = *(const unsigned*)(H + (size_t)s0 * D + co);
    acc0 += __uint_as_float(d0 << 16);
    acc1 += __uint_as_float(d0 & 0xffff0000u);
  }
  // reduce over the 4 edge-groups
  acc0 += __shfl_xor(acc0, 16); acc0 += __shfl_xor(acc0, 32);
  acc1 += __shfl_xor(acc1, 16); acc1 += __shfl_xor(acc1, 32);
  if (eg == 0) {
    unsigned sd = *(const unsigned*)(H + (size_t)node * D + co);  // self row
    float di = dinv[g * NN + node];
    float2 bb = *(const float2*)(bias + slice * 32 + l16 * 2);
    float v0 = fmaf(acc0 + __uint_as_float(sd << 16), di, bb.x);
    float v1 = fmaf(acc1 + __uint_as_float(sd & 0xffff0000u), di, bb.y);
    if constexpr (RELU) { v0 = fmaxf(v0, 0.f); v1 = fmaxf(v1, 0.f); }
    if constexpr (sizeof(OutT) == 2) {
      unsigned p = ((unsigned)f2bf(v1) << 16) | (unsigned)f2bf(v0);
      *(unsigned*)((unsigned short*)Ob + (size_t)g * ogstride + (size_t)node * D + co) = p;
    } else {
      float2 r; r.x = v0; r.y = v1;
      *(float2*)((float*)Ob + (size_t)g * ogstride + (size_t)node * D + co) = r;
    }
  }
}

// ---------------- launch ----------------

extern "C" void kernel_launch(void* const* d_in, const int* in_sizes, int n_in,
                              void* d_out, int out_size, void* d_ws, size_t ws_size,
                              hipStream_t stream) {
  const float* x1 = (const float*)d_in[0];
  const int* e1 = (const int*)d_in[1];
  const float* x2 = (const float*)d_in[2];
  const int* e2 = (const int*)d_in[3];
  const float* W1 = (const float*)d_in[4];
  const float* b1 = (const float*)d_in[5];
  const float* W2 = (const float*)d_in[6];
  const float* b2 = (const float*)d_in[7];
  float* out = (float*)d_out;

  char* base = (char*)d_ws;
  size_t off = 0;
  auto alloc = [&](size_t bytes) -> void* {
    void* p = base + off;
    off = (off + bytes + 511) & ~(size_t)511;
    return p;
  };
  int* counts = (int*)alloc((size_t)2 * NN * 4);
  int* rowptr = (int*)alloc((size_t)2 * (NN + 1) * 4);
  int* cursor = (int*)alloc((size_t)2 * NN * 4);
  float* dinv = (float*)alloc((size_t)2 * NN * 4);
  int* bsum = (int*)alloc((size_t)2 * NCH * 4);
  unsigned short* col = (unsigned short*)alloc((size_t)2 * NE * 2);
  unsigned short* m1 = (unsigned short*)alloc((size_t)2 * NN * DHID * 2);  // also reused as m2
  unsigned short* a1 = (unsigned short*)alloc((size_t)2 * NN * DHID * 2);
  unsigned short* P1 = (unsigned short*)alloc((size_t)8 * 16 * 64 * 8 * 2);
  unsigned short* P2 = (unsigned short*)alloc((size_t)8 * 8 * 64 * 8 * 2);

  hipMemsetAsync(counts, 0, (size_t)2 * NN * 4, stream);
  hist_kernel<<<dim3((NE + 255) / 256, 2), 256, 0, stream>>>(e1, e2, counts);
  scanA_kernel<<<dim3(NCH, 2), 256, 0, stream>>>(counts, bsum);
  scanB_kernel<<<2, 256, 0, stream>>>(bsum, rowptr);
  scanC_kernel<<<dim3(NCH, 2), 256, 0, stream>>>(counts, bsum, rowptr, cursor, dinv);
  scatter_kernel<<<dim3((NE + 255) / 256, 2), 256, 0, stream>>>(e1, e2, cursor, col);
  pack_kernel<<<(98304 + 255) / 256, 256, 0, stream>>>(W1, W2, P1, P2);
  // layer 1: m1 = (x @ W1) * dinv (bf16), sliced agg+scale+bias+relu -> a1
  mm_kernel<DHID, true><<<dim3((NN + 63) / 64, 2), 256, 0, stream>>>(
      x1, x2, P1, m1, dinv, (long long)NN * DHID);
  agg_kernel<DHID, 8, true, unsigned short><<<8 * (NN / 4) * 2, 256, 0, stream>>>(
      m1, a1, rowptr, col, dinv, b1, (long long)NN * DHID, (long long)NN * DHID);
  // layer 2: m2 = (a1 @ W2) * dinv (into m1 buffer), sliced agg+scale+bias -> d_out
  mm_kernel<DOUT, false><<<dim3((NN + 63) / 64, 2), 256, 0, stream>>>(
      a1, a1 + (size_t)NN * DHID, P2, m1, dinv, (long long)NN * DHID);
  agg_kernel<DOUT, 4, false, float><<<4 * (NN / 4) * 2, 256, 0, stream>>>(
      m1, out, rowptr, col, dinv, b2, (long long)NN * DHID, (long long)NN * DOUT);
}

// Round 6
// 568.622 us; speedup vs baseline: 1.4572x; 1.4572x over previous
//
#include <hip/hip_runtime.h>

typedef __bf16 bf16x8 __attribute__((ext_vector_type(8)));
typedef float f32x4 __attribute__((ext_vector_type(4)));

constexpr int NN = 50000;   // nodes
constexpr int NE = 800000;  // edges
constexpr int DIN = 256, DHID = 256, DOUT = 128;
constexpr int NCH = (NN + 255) / 256;  // 196 chunks of 256

__device__ __forceinline__ unsigned short f2bf(float f) {
  unsigned u = __float_as_uint(f);
  u += 0x7fffu + ((u >> 16) & 1u);  // RNE
  return (unsigned short)(u >> 16);
}
__device__ __forceinline__ float bf2f(unsigned short h) {
  return __uint_as_float(((unsigned)h) << 16);
}

// ---------------- CSR build ----------------

__global__ void hist_kernel(const int* __restrict__ e0, const int* __restrict__ e1,
                            int* __restrict__ counts) {
  int g = blockIdx.y;
  const int* dst = (g ? e1 : e0) + NE;  // edge_index row 1
  int* c = counts + g * NN;
  int i = blockIdx.x * blockDim.x + threadIdx.x;
  if (i < NE) atomicAdd(&c[dst[i]], 1);
}

// 3-phase hierarchical exclusive scan of counts -> rowptr/cursor (+dinv)

__global__ __launch_bounds__(256) void scanA_kernel(const int* __restrict__ counts,
                                                    int* __restrict__ bsum) {
  int g = blockIdx.y, chunk = blockIdx.x, t = threadIdx.x;
  int i = chunk * 256 + t;
  int v = (i < NN) ? counts[g * NN + i] : 0;
  __shared__ int sh[256];
  sh[t] = v;
  __syncthreads();
  for (int off = 128; off > 0; off >>= 1) {
    if (t < off) sh[t] += sh[t + off];
    __syncthreads();
  }
  if (t == 0) bsum[g * NCH + chunk] = sh[0];
}

__global__ __launch_bounds__(256) void scanB_kernel(int* __restrict__ bsum,
                                                    int* __restrict__ rowptr) {
  int g = blockIdx.x, t = threadIdx.x;
  int v = (t < NCH) ? bsum[g * NCH + t] : 0;
  __shared__ int sh[256];
  sh[t] = v;
  __syncthreads();
  for (int off = 1; off < 256; off <<= 1) {
    int x = (t >= off) ? sh[t - off] : 0;
    __syncthreads();
    if (t >= off) sh[t] += x;
    __syncthreads();
  }
  if (t < NCH) bsum[g * NCH + t] = sh[t] - v;  // exclusive base
  if (t == 255) rowptr[g * (NN + 1) + NN] = sh[255];
}

__global__ __launch_bounds__(256) void scanC_kernel(const int* __restrict__ counts,
                                                    const int* __restrict__ bsum,
                                                    int* __restrict__ rowptr,
                                                    int* __restrict__ cursor,
                                                    float* __restrict__ dinv) {
  int g = blockIdx.y, chunk = blockIdx.x, t = threadIdx.x;
  int i = chunk * 256 + t;
  int v = (i < NN) ? counts[g * NN + i] : 0;
  __shared__ int sh[256];
  sh[t] = v;
  __syncthreads();
  for (int off = 1; off < 256; off <<= 1) {
    int x = (t >= off) ? sh[t - off] : 0;
    __syncthreads();
    if (t >= off) sh[t] += x;
    __syncthreads();
  }
  if (i < NN) {
    int run = bsum[g * NCH + chunk] + sh[t] - v;
    rowptr[g * (NN + 1) + i] = run;
    cursor[g * NN + i] = run;
    dinv[g * NN + i] = rsqrtf((float)(v + 1));  // +1 self-loop
  }
}

__global__ void scatter_kernel(const int* __restrict__ e0, const int* __restrict__ e1,
                               int* __restrict__ cursor, unsigned short* __restrict__ col) {
  int g = blockIdx.y;
  const int* e = g ? e1 : e0;
  int* cur = cursor + g * NN;
  unsigned short* cl = col + g * NE;
  int i = blockIdx.x * blockDim.x + threadIdx.x;
  if (i < NE) {
    int s = e[i], d = e[NE + i];
    int slot = atomicAdd(&cur[d], 1);
    cl[slot] = (unsigned short)s;
  }
}

// ---------------- Pack W into B-fragment order ----------------
// Wpack flat index: ((kb*NT + nt)*64 + lane)*8 + j  holds W[kb*32 + (lane>>4)*8 + j][nt*16 + (lane&15)]

__global__ void pack_kernel(const float* __restrict__ W1, const float* __restrict__ W2,
                            unsigned short* __restrict__ P1, unsigned short* __restrict__ P2) {
  int i = blockIdx.x * blockDim.x + threadIdx.x;
  constexpr int N1 = 8 * 16 * 64 * 8;  // 65536 (K=256, N=256)
  constexpr int N2 = 8 * 8 * 64 * 8;   // 32768 (K=256, N=128)
  if (i < N1) {
    int j = i & 7, lane = (i >> 3) & 63, grp = i >> 9;
    int nt = grp & 15, kb = grp >> 4;
    int k = kb * 32 + (lane >> 4) * 8 + j;
    int n = nt * 16 + (lane & 15);
    P1[i] = f2bf(W1[k * DHID + n]);
  } else if (i < N1 + N2) {
    int ii = i - N1;
    int j = ii & 7, lane = (ii >> 3) & 63, grp = ii >> 9;
    int nt = grp & 7, kb = grp >> 3;
    int k = kb * 32 + (lane >> 4) * 8 + j;
    int n = nt * 16 + (lane & 15);
    P2[ii] = f2bf(W2[k * DOUT + n]);
  }
}

// ---------------- MFMA matmul (layer 1): m1 = (x @ W1) * dinv[row] ----------------

__global__ __launch_bounds__(256) void mm1_kernel(
    const float* __restrict__ A0, const float* __restrict__ A1,
    const unsigned short* __restrict__ Wp, unsigned short* __restrict__ Cb,
    const float* __restrict__ dinv) {
  constexpr int N = DHID, NT = N / 16, K = 256;
  int g = blockIdx.y;
  const float* A = g ? A1 : A0;
  unsigned short* C = Cb + (size_t)g * NN * N;
  const float* dv = dinv + g * NN;
  int wave = threadIdx.x >> 6, lane = threadIdx.x & 63;
  int q = lane >> 4, lm = lane & 15;
  int m0 = blockIdx.x * 64 + wave * 16;
  int rowc = min(m0 + lm, NN - 1);
  f32x4 acc[NT];
#pragma unroll
  for (int nt = 0; nt < NT; nt++) acc[nt] = (f32x4){0.f, 0.f, 0.f, 0.f};
#pragma unroll
  for (int kb = 0; kb < K / 32; kb++) {
    int kc = kb * 32 + q * 8;  // lane's contiguous k-chunk (A frag: k = quad*8+j)
    const float* Af = A + (size_t)rowc * K + kc;
    const float4 v0 = *(const float4*)Af;
    const float4 v1 = *(const float4*)(Af + 4);
    bf16x8 a;
    a[0] = (__bf16)v0.x; a[1] = (__bf16)v0.y; a[2] = (__bf16)v0.z; a[3] = (__bf16)v0.w;
    a[4] = (__bf16)v1.x; a[5] = (__bf16)v1.y; a[6] = (__bf16)v1.z; a[7] = (__bf16)v1.w;
#pragma unroll
    for (int nt = 0; nt < NT; nt++) {
      bf16x8 b = *(const bf16x8*)(Wp + (((size_t)kb * NT + nt) * 64 + lane) * 8);
      acc[nt] = __builtin_amdgcn_mfma_f32_16x16x32_bf16(a, b, acc[nt], 0, 0, 0);
    }
  }
  // C/D layout: col = lane&15, row = quad*4 + reg
  float dvr[4];
#pragma unroll
  for (int r = 0; r < 4; r++) dvr[r] = dv[min(m0 + q * 4 + r, NN - 1)];
#pragma unroll
  for (int nt = 0; nt < NT; nt++) {
#pragma unroll
    for (int r = 0; r < 4; r++) {
      int grow = m0 + q * 4 + r;
      if (grow < NN) C[(size_t)grow * N + nt * 16 + lm] = f2bf(acc[nt][r] * dvr[r]);
    }
  }
}

// ---------- Fused agg1 + mm2: block = 16 nodes ----------
// Phase 1 (round-4 agg structure): each wave aggregates 4 nodes serially; lane
// covers 4 cols; 16-deep unrolled gather (512 B/row contiguous per instruction).
// Result (= relu((agg+self)*dinv + b1) = a1 row) goes to LDS bf16 (stride
// padded +8 elem -> 2-way banks, free). Phase 2: 16x128 MFMA tile vs packed W2;
// epilogue prescales by dinv[row], writes m2.

__global__ __launch_bounds__(256) void agg1mm2_kernel(
    const unsigned short* __restrict__ m1b, const unsigned short* __restrict__ P2,
    unsigned short* __restrict__ m2b, const int* __restrict__ rowptr,
    const unsigned short* __restrict__ col, const float* __restrict__ dinv,
    const float* __restrict__ b1) {
  constexpr int LDW = DHID + 8;  // 264 elem = 528 B row stride
  __shared__ unsigned short sha[16 * LDW];
  int g = blockIdx.y;
  const unsigned short* H = m1b + (size_t)g * NN * DHID;
  unsigned short* M2 = m2b + (size_t)g * NN * DOUT;
  const int* rp = rowptr + g * (NN + 1);
  const unsigned short* cl = col + (size_t)g * NE;
  const float* dv = dinv + g * NN;
  int wave = threadIdx.x >> 6, lane = threadIdx.x & 63;
  int base = blockIdx.x * 16;
  float4 bb = *(const float4*)(b1 + lane * 4);
  // ---- phase 1: gather-aggregate 4 nodes per wave ----
  for (int n = 0; n < 4; n++) {
    int node = base + wave * 4 + n;
    ushort4 sv = *(const ushort4*)(H + (size_t)node * DHID + lane * 4);
    float a0 = bf2f(sv.x), a1v = bf2f(sv.y), a2 = bf2f(sv.z), a3 = bf2f(sv.w);
    int jb = rp[node], je = rp[node + 1];
    int j = jb;
    for (; j + 16 <= je; j += 16) {
      int s[16];
      ushort4 v[16];
#pragma unroll
      for (int u = 0; u < 16; u++) s[u] = cl[j + u];
#pragma unroll
      for (int u = 0; u < 16; u++) v[u] = *(const ushort4*)(H + (size_t)s[u] * DHID + lane * 4);
#pragma unroll
      for (int u = 0; u < 16; u++) {
        a0 += bf2f(v[u].x); a1v += bf2f(v[u].y);
        a2 += bf2f(v[u].z); a3 += bf2f(v[u].w);
      }
    }
    for (; j + 8 <= je; j += 8) {
      int s[8];
      ushort4 v[8];
#pragma unroll
      for (int u = 0; u < 8; u++) s[u] = cl[j + u];
#pragma unroll
      for (int u = 0; u < 8; u++) v[u] = *(const ushort4*)(H + (size_t)s[u] * DHID + lane * 4);
#pragma unroll
      for (int u = 0; u < 8; u++) {
        a0 += bf2f(v[u].x); a1v += bf2f(v[u].y);
        a2 += bf2f(v[u].z); a3 += bf2f(v[u].w);
      }
    }
    for (; j < je; j++) {
      int s = cl[j];
      ushort4 hv = *(const ushort4*)(H + (size_t)s * DHID + lane * 4);
      a0 += bf2f(hv.x); a1v += bf2f(hv.y);
      a2 += bf2f(hv.z); a3 += bf2f(hv.w);
    }
    float di = dv[node];
    a0 = fmaxf(fmaf(a0, di, bb.x), 0.f); a1v = fmaxf(fmaf(a1v, di, bb.y), 0.f);
    a2 = fmaxf(fmaf(a2, di, bb.z), 0.f); a3 = fmaxf(fmaf(a3, di, bb.w), 0.f);
    ushort4 o;
    o.x = f2bf(a0); o.y = f2bf(a1v); o.z = f2bf(a2); o.w = f2bf(a3);
    *(ushort4*)(sha + (wave * 4 + n) * LDW + lane * 4) = o;
  }
  __syncthreads();
  // ---- phase 2: 16x128 tile = A(16x256 from LDS) @ W2 ----
  int q = lane >> 4, lm = lane & 15;
  f32x4 acc[2];
  acc[0] = (f32x4){0.f, 0.f, 0.f, 0.f};
  acc[1] = (f32x4){0.f, 0.f, 0.f, 0.f};
  constexpr int NT2 = DOUT / 16;  // 8
#pragma unroll
  for (int kb = 0; kb < 8; kb++) {
    bf16x8 a = *(const bf16x8*)(sha + lm * LDW + kb * 32 + q * 8);
#pragma unroll
    for (int t = 0; t < 2; t++) {
      int nt = wave * 2 + t;
      bf16x8 b = *(const bf16x8*)(P2 + (((size_t)kb * NT2 + nt) * 64 + lane) * 8);
      acc[t] = __builtin_amdgcn_mfma_f32_16x16x32_bf16(a, b, acc[t], 0, 0, 0);
    }
  }
  float dvr[4];
#pragma unroll
  for (int r = 0; r < 4; r++) dvr[r] = dv[base + q * 4 + r];
#pragma unroll
  for (int t = 0; t < 2; t++) {
#pragma unroll
    for (int r = 0; r < 4; r++) {
      int node = base + q * 4 + r;
      M2[(size_t)node * DOUT + (wave * 2 + t) * 16 + lm] = f2bf(acc[t][r] * dvr[r]);
    }
  }
}

// ---------------- agg2 (round-4 form): gather m2, +self, *dinv, +bias -> out ----

__global__ __launch_bounds__(256) void agg2_kernel(
    const unsigned short* __restrict__ m2, float* __restrict__ out,
    const int* __restrict__ rowptr, const unsigned short* __restrict__ col,
    const float* __restrict__ dinv, const float* __restrict__ b2) {
  int g = blockIdx.y;
  const unsigned short* H = m2 + (size_t)g * NN * DOUT;
  float* O = out + (size_t)g * NN * DOUT;
  const int* rp = rowptr + g * (NN + 1);
  const unsigned short* cl = col + (size_t)g * NE;
  const float* dv = dinv + g * NN;
  int node = blockIdx.x * 4 + (threadIdx.x >> 6);
  if (node >= NN) return;
  int lane = threadIdx.x & 63;
  ushort2 sv = *(const ushort2*)(H + (size_t)node * DOUT + lane * 2);
  float a0 = bf2f(sv.x), a1v = bf2f(sv.y);
  int jb = rp[node], je = rp[node + 1];
  int j = jb;
  for (; j + 16 <= je; j += 16) {
    int s[16];
    ushort2 v[16];
#pragma unroll
    for (int u = 0; u < 16; u++) s[u] = cl[j + u];
#pragma unroll
    for (int u = 0; u < 16; u++) v[u] = *(const ushort2*)(H + (size_t)s[u] * DOUT + lane * 2);
#pragma unroll
    for (int u = 0; u < 16; u++) { a0 += bf2f(v[u].x); a1v += bf2f(v[u].y); }
  }
  for (; j + 8 <= je; j += 8) {
    int s[8];
    ushort2 v[8];
#pragma unroll
    for (int u = 0; u < 8; u++) s[u] = cl[j + u];
#pragma unroll
    for (int u = 0; u < 8; u++) v[u] = *(const ushort2*)(H + (size_t)s[u] * DOUT + lane * 2);
#pragma unroll
    for (int u = 0; u < 8; u++) { a0 += bf2f(v[u].x); a1v += bf2f(v[u].y); }
  }
  for (; j < je; j++) {
    int s = cl[j];
    ushort2 hv = *(const ushort2*)(H + (size_t)s * DOUT + lane * 2);
    a0 += bf2f(hv.x); a1v += bf2f(hv.y);
  }
  float di = dv[node];
  float2 bbv = *(const float2*)(b2 + lane * 2);
  float2 res;
  res.x = fmaf(a0, di, bbv.x); res.y = fmaf(a1v, di, bbv.y);
  *(float2*)(O + (size_t)node * DOUT + lane * 2) = res;
}

// ---------------- launch ----------------

extern "C" void kernel_launch(void* const* d_in, const int* in_sizes, int n_in,
                              void* d_out, int out_size, void* d_ws, size_t ws_size,
                              hipStream_t stream) {
  const float* x1 = (const float*)d_in[0];
  const int* e1 = (const int*)d_in[1];
  const float* x2 = (const float*)d_in[2];
  const int* e2 = (const int*)d_in[3];
  const float* W1 = (const float*)d_in[4];
  const float* b1 = (const float*)d_in[5];
  const float* W2 = (const float*)d_in[6];
  const float* b2 = (const float*)d_in[7];
  float* out = (float*)d_out;

  char* base = (char*)d_ws;
  size_t off = 0;
  auto alloc = [&](size_t bytes) -> void* {
    void* p = base + off;
    off = (off + bytes + 511) & ~(size_t)511;
    return p;
  };
  int* counts = (int*)alloc((size_t)2 * NN * 4);
  int* rowptr = (int*)alloc((size_t)2 * (NN + 1) * 4);
  int* cursor = (int*)alloc((size_t)2 * NN * 4);
  float* dinv = (float*)alloc((size_t)2 * NN * 4);
  int* bsum = (int*)alloc((size_t)2 * NCH * 4);
  unsigned short* col = (unsigned short*)alloc((size_t)2 * NE * 2);
  unsigned short* m1 = (unsigned short*)alloc((size_t)2 * NN * DHID * 2);
  unsigned short* m2 = (unsigned short*)alloc((size_t)2 * NN * DOUT * 2);
  unsigned short* P1 = (unsigned short*)alloc((size_t)8 * 16 * 64 * 8 * 2);
  unsigned short* P2 = (unsigned short*)alloc((size_t)8 * 8 * 64 * 8 * 2);

  hipMemsetAsync(counts, 0, (size_t)2 * NN * 4, stream);
  hist_kernel<<<dim3((NE + 255) / 256, 2), 256, 0, stream>>>(e1, e2, counts);
  scanA_kernel<<<dim3(NCH, 2), 256, 0, stream>>>(counts, bsum);
  scanB_kernel<<<2, 256, 0, stream>>>(bsum, rowptr);
  scanC_kernel<<<dim3(NCH, 2), 256, 0, stream>>>(counts, bsum, rowptr, cursor, dinv);
  scatter_kernel<<<dim3((NE + 255) / 256, 2), 256, 0, stream>>>(e1, e2, cursor, col);
  pack_kernel<<<(98304 + 255) / 256, 256, 0, stream>>>(W1, W2, P1, P2);
  // layer 1 mm: m1 = (x @ W1) * dinv (bf16)
  mm1_kernel<<<dim3((NN + 63) / 64, 2), 256, 0, stream>>>(x1, x2, P1, m1, dinv);
  // fused: a1 = relu(agg(m1)*dinv + b1) -> LDS -> m2 = (a1 @ W2) * dinv
  agg1mm2_kernel<<<dim3(NN / 16, 2), 256, 0, stream>>>(m1, P2, m2, rowptr, col, dinv, b1);
  // layer 2 agg: out = agg(m2)*dinv + b2 (fp32)
  agg2_kernel<<<dim3(NN / 4, 2), 256, 0, stream>>>(m2, out, rowptr, col, dinv, b2);
}